// Round 1
// baseline (317.789 us; speedup 1.0000x reference)
//
#include <hip/hip_runtime.h>
#include <math.h>

#define VOCAB 32000
#define BATCH 16
#define SEQ   512

// ---------------------------------------------------------------------------
// Kernel 1: argmax over vocab axis. One block per (b,s) position.
// 256 threads, float4 loads, first-occurrence tie-break (matches jnp.argmax).
// ---------------------------------------------------------------------------
__global__ __launch_bounds__(256) void argmax_kernel(const float* __restrict__ logits,
                                                     int* __restrict__ words) {
    const int pos = blockIdx.x;                       // 0 .. BATCH*SEQ-1
    const float4* base4 = (const float4*)(logits + (size_t)pos * VOCAB);

    const int tid = threadIdx.x;
    float best = -INFINITY;
    int bestIdx = 0x7FFFFFFF;

    // 32000/4 = 8000 float4 elements, stride-256 coalesced.
    for (int k = tid; k < VOCAB / 4; k += 256) {
        float4 v = base4[k];
        int i0 = k * 4;
        // strict > keeps the first (lowest-index) max within this lane,
        // since this lane's indices are visited in increasing order.
        if (v.x > best) { best = v.x; bestIdx = i0;     }
        if (v.y > best) { best = v.y; bestIdx = i0 + 1; }
        if (v.z > best) { best = v.z; bestIdx = i0 + 2; }
        if (v.w > best) { best = v.w; bestIdx = i0 + 3; }
    }

    // wave (64-lane) reduction with lower-index tie-break
    for (int off = 32; off > 0; off >>= 1) {
        float ov = __shfl_down(best, off, 64);
        int   oi = __shfl_down(bestIdx, off, 64);
        if (ov > best || (ov == best && oi < bestIdx)) { best = ov; bestIdx = oi; }
    }

    __shared__ float sv[4];
    __shared__ int   si[4];
    const int wid = tid >> 6;
    if ((tid & 63) == 0) { sv[wid] = best; si[wid] = bestIdx; }
    __syncthreads();

    if (tid == 0) {
        for (int w = 1; w < 4; ++w) {
            if (sv[w] > best || (sv[w] == best && si[w] < bestIdx)) {
                best = sv[w]; bestIdx = si[w];
            }
        }
        words[pos] = bestIdx;
    }
}

// ---------------------------------------------------------------------------
// Kernel 2: Levenshtein DP via anti-diagonal wavefront.
// One block (512 threads) per batch row. Thread t owns DP row i = t+1.
// diag_d[i] = D[i][d-i]. Three rotating LDS diagonals.
//   up   = D[i-1][j]   = diag_{d-1}[i-1]
//   left = D[i][j-1]   = diag_{d-1}[i]
//   diag = D[i-1][j-1] = diag_{d-2}[i-1]
// ---------------------------------------------------------------------------
__global__ __launch_bounds__(512) void editdist_kernel(const int* __restrict__ words,
                                                       const int* __restrict__ target,
                                                       float* __restrict__ dist) {
    const int b = blockIdx.x;
    const int t = threadIdx.x;

    __shared__ int dA[SEQ + 1], dB[SEQ + 1], dC[SEQ + 1];
    __shared__ int s_ow[SEQ], s_tg[SEQ];

    s_ow[t] = words[b * SEQ + t];
    s_tg[t] = target[b * SEQ + t];

    if (t == 0) {
        dA[0] = 0;              // diag d=0: D[0][0]
        dB[0] = 1; dB[1] = 1;   // diag d=1: D[0][1], D[1][0]
    }
    __syncthreads();

    int* pm2 = dA;   // diag d-2
    int* pm1 = dB;   // diag d-1
    int* pc  = dC;   // diag d (being written)

    const int i = t + 1;        // DP row owned by this thread
    const int myw = s_ow[i - 1];

    for (int d = 2; d <= 2 * SEQ; ++d) {
        // boundary cells of diagonal d
        if (t == 0 && d <= SEQ) {
            pc[0] = d;          // D[0][d]
            pc[d] = d;          // D[d][0]
        }
        const int j = d - i;
        if (j >= 1 && j <= SEQ) {
            const int up   = pm1[i - 1];
            const int left = pm1[i];
            const int dg   = pm2[i - 1];
            int mn = up < left ? up : left;
            mn = mn < dg ? mn : dg;
            pc[i] = (myw == s_tg[j - 1]) ? dg : (mn + 1);
        }
        __syncthreads();
        int* tmp = pm2; pm2 = pm1; pm1 = pc; pc = tmp;
    }

    // after last rotation, pm1 holds diag d = 2*SEQ; answer at i = SEQ
    if (t == 0) dist[b] = (float)pm1[SEQ];
}

// ---------------------------------------------------------------------------
// Kernel 3: mean(dist / SEQ)
// ---------------------------------------------------------------------------
__global__ void finalize_kernel(const float* __restrict__ dist, float* __restrict__ out) {
    if (threadIdx.x == 0 && blockIdx.x == 0) {
        float s = 0.0f;
        for (int b = 0; b < BATCH; ++b) s += dist[b];
        out[0] = s / ((float)BATCH * (float)SEQ);
    }
}

extern "C" void kernel_launch(void* const* d_in, const int* in_sizes, int n_in,
                              void* d_out, int out_size, void* d_ws, size_t ws_size,
                              hipStream_t stream) {
    const float* logits = (const float*)d_in[0];
    const int*   target = (const int*)d_in[1];

    int*   words = (int*)d_ws;                                   // BATCH*SEQ ints
    float* dist  = (float*)((char*)d_ws + BATCH * SEQ * sizeof(int)); // BATCH floats

    argmax_kernel<<<BATCH * SEQ, 256, 0, stream>>>(logits, words);
    editdist_kernel<<<BATCH, 512, 0, stream>>>(words, target, dist);
    finalize_kernel<<<1, 64, 0, stream>>>(dist, (float*)d_out);
}

// Round 2
// 270.891 us; speedup vs baseline: 1.1731x; 1.1731x over previous
//
#include <hip/hip_runtime.h>
#include <math.h>

#define VOCAB 32000
#define BATCH 16
#define SEQ   512

// ---------------------------------------------------------------------------
// Kernel 1: argmax over vocab axis. One block per (b,s) position.
// 256 threads, float4 loads, first-occurrence tie-break (matches jnp.argmax).
// Memory-bound: each block streams a contiguous 128 KB row.
// ---------------------------------------------------------------------------
__global__ __launch_bounds__(256) void argmax_kernel(const float* __restrict__ logits,
                                                     int* __restrict__ words) {
    const int pos = blockIdx.x;                       // 0 .. BATCH*SEQ-1
    const float4* base4 = (const float4*)(logits + (size_t)pos * VOCAB);

    const int tid = threadIdx.x;
    float best = -INFINITY;
    int bestIdx = 0x7FFFFFFF;

    // 32000/4 = 8000 float4 elements, stride-256 coalesced.
    for (int k = tid; k < VOCAB / 4; k += 256) {
        float4 v = base4[k];
        int i0 = k * 4;
        if (v.x > best) { best = v.x; bestIdx = i0;     }
        if (v.y > best) { best = v.y; bestIdx = i0 + 1; }
        if (v.z > best) { best = v.z; bestIdx = i0 + 2; }
        if (v.w > best) { best = v.w; bestIdx = i0 + 3; }
    }

    // wave (64-lane) reduction with lower-index tie-break
    for (int off = 32; off > 0; off >>= 1) {
        float ov = __shfl_down(best, off, 64);
        int   oi = __shfl_down(bestIdx, off, 64);
        if (ov > best || (ov == best && oi < bestIdx)) { best = ov; bestIdx = oi; }
    }

    __shared__ float sv[4];
    __shared__ int   si[4];
    const int wid = tid >> 6;
    if ((tid & 63) == 0) { sv[wid] = best; si[wid] = bestIdx; }
    __syncthreads();

    if (tid == 0) {
        for (int w = 1; w < 4; ++w) {
            if (sv[w] > best || (sv[w] == best && si[w] < bestIdx)) {
                best = sv[w]; bestIdx = si[w];
            }
        }
        words[pos] = bestIdx;
    }
}

// ---------------------------------------------------------------------------
// Kernel 2: Levenshtein DP — single-wave staggered column march (no barriers).
// One 64-lane wave per batch row. Lane t owns DP rows t*8+1 .. t*8+8, held in
// registers. At step s, lane t processes column j = s - t. The lane's bottom
// row value D[(t+1)*8][j] flows to lane t+1 via __shfl_up next step.
// Recurrence: D[i][j] = min3(up, left, diag - eq) + 1   (eq in {0,1}),
// equivalent to the reference since diag <= up+1 and diag <= left+1 always.
// ---------------------------------------------------------------------------
#define RPL 8   // rows per lane

__global__ __launch_bounds__(64) void editdist_kernel(const int* __restrict__ words,
                                                      const int* __restrict__ target,
                                                      float* __restrict__ dist) {
    const int b = blockIdx.x;
    const int t = threadIdx.x;      // lane 0..63

    __shared__ int s_tg[SEQ];
    #pragma unroll
    for (int k = 0; k < RPL; ++k)
        s_tg[t + 64 * k] = target[b * SEQ + t + 64 * k];
    // single wave: LDS writes complete before reads after waitcnt; compiler
    // inserts lgkmcnt. __syncthreads for safety (1 wave -> cheap, once).
    __syncthreads();

    int myw[RPL];
    #pragma unroll
    for (int r = 0; r < RPL; ++r)
        myw[r] = words[b * SEQ + t * RPL + r];

    // column-0 init: colv[r] = D[t*8+1+r][0] = t*8+1+r ; prev_up = D[t*8][0]
    int colv[RPL];
    #pragma unroll
    for (int r = 0; r < RPL; ++r) colv[r] = t * RPL + 1 + r;
    int prev_up = t * RPL;

    const int NSTEP = SEQ + 64 - 1;   // 575
    for (int s = 1; s <= NSTEP; ++s) {
        // value of D[t*8][j] produced by lane t-1 last step (its colv[7])
        int up_in = __shfl_up(colv[RPL - 1], 1, 64);
        const int j = s - t;
        if (t == 0) up_in = s;            // D[0][j] = j
        if (j >= 1 && j <= SEQ) {
            const int tgj = s_tg[j - 1];
            int u  = up_in;               // D[i-1][j]
            int dg = prev_up;             // D[i-1][j-1]
            #pragma unroll
            for (int r = 0; r < RPL; ++r) {
                const int left = colv[r];              // D[i][j-1]
                const int de = dg - (myw[r] == tgj ? 1 : 0);
                int mn = u < left ? u : left;
                mn = mn < de ? mn : de;
                const int nc = mn + 1;
                dg = left;                // old left becomes next row's diag
                colv[r] = nc;
                u = nc;                   // becomes next row's up
            }
            prev_up = up_in;              // D[t*8][j] -> next column's diag
        }
    }

    if (t == 63) dist[b] = (float)colv[RPL - 1];   // D[512][512]
}

// ---------------------------------------------------------------------------
// Kernel 3: mean(dist / SEQ)
// ---------------------------------------------------------------------------
__global__ void finalize_kernel(const float* __restrict__ dist, float* __restrict__ out) {
    if (threadIdx.x == 0 && blockIdx.x == 0) {
        float s = 0.0f;
        for (int b = 0; b < BATCH; ++b) s += dist[b];
        out[0] = s / ((float)BATCH * (float)SEQ);
    }
}

extern "C" void kernel_launch(void* const* d_in, const int* in_sizes, int n_in,
                              void* d_out, int out_size, void* d_ws, size_t ws_size,
                              hipStream_t stream) {
    const float* logits = (const float*)d_in[0];
    const int*   target = (const int*)d_in[1];

    int*   words = (int*)d_ws;                                        // BATCH*SEQ ints
    float* dist  = (float*)((char*)d_ws + BATCH * SEQ * sizeof(int)); // BATCH floats

    argmax_kernel<<<BATCH * SEQ, 256, 0, stream>>>(logits, words);
    editdist_kernel<<<BATCH, 64, 0, stream>>>(words, target, dist);
    finalize_kernel<<<1, 64, 0, stream>>>(dist, (float*)d_out);
}

// Round 4
// 252.833 us; speedup vs baseline: 1.2569x; 1.0714x over previous
//
#include <hip/hip_runtime.h>
#include <math.h>

#define VOCAB 32000
#define BATCH 16
#define SEQ   512
#define RPL   8   // DP rows per lane in editdist

typedef float floatx4 __attribute__((ext_vector_type(4)));

// ---------------------------------------------------------------------------
// Kernel 1: argmax over vocab axis. One WAVE per (b,s) row; 4 waves/block.
// Each wave streams a contiguous 128 KB row with nontemporal float4 loads.
// First-occurrence tie-break (strict > in-lane, lower-index in reduction)
// matches jnp.argmax. Also zeroes out[0] for the fused finalize.
// ---------------------------------------------------------------------------
__global__ __launch_bounds__(256) void argmax_kernel(const float* __restrict__ logits,
                                                     int* __restrict__ words,
                                                     float* __restrict__ out) {
    if (blockIdx.x == 0 && threadIdx.x == 0) out[0] = 0.0f;

    const int wid  = threadIdx.x >> 6;          // wave in block: 0..3
    const int lane = threadIdx.x & 63;
    const int row  = blockIdx.x * 4 + wid;      // 0 .. BATCH*SEQ-1
    const floatx4* base4 = (const floatx4*)(logits + (size_t)row * VOCAB);

    float best = -INFINITY;
    int bestIdx = 0x7FFFFFFF;

    // 8000 float4 / 64 lanes = 125 iterations, contiguous 1 KB per wave-step.
    #pragma unroll 5
    for (int k = lane; k < VOCAB / 4; k += 64) {
        floatx4 v = __builtin_nontemporal_load(base4 + k);
        int i0 = k * 4;
        if (v.x > best) { best = v.x; bestIdx = i0;     }
        if (v.y > best) { best = v.y; bestIdx = i0 + 1; }
        if (v.z > best) { best = v.z; bestIdx = i0 + 2; }
        if (v.w > best) { best = v.w; bestIdx = i0 + 3; }
    }

    // 64-lane reduction, lower-index tie-break
    for (int off = 32; off > 0; off >>= 1) {
        float ov = __shfl_down(best, off, 64);
        int   oi = __shfl_down(bestIdx, off, 64);
        if (ov > best || (ov == best && oi < bestIdx)) { best = ov; bestIdx = oi; }
    }
    if (lane == 0) words[row] = bestIdx;
}

// ---------------------------------------------------------------------------
// Kernel 2: Levenshtein DP — single-wave staggered column march, no barriers.
// Lane t owns DP rows t*8+1..t*8+8 in registers; at step s it processes
// column j = s - t. Off-chain precompute mp[r] = min(left, diag-eq)+1 keeps
// the serial chain at 2 ops/row: u = min(u+1, mp[r]).
// Fused finalize: lane 63 atomicAdds dist/(B*S) into out[0].
// ---------------------------------------------------------------------------
__global__ __launch_bounds__(64) void editdist_kernel(const int* __restrict__ words,
                                                      const int* __restrict__ target,
                                                      float* __restrict__ out) {
    const int b = blockIdx.x;
    const int t = threadIdx.x;      // lane 0..63

    __shared__ int s_tg[SEQ];
    #pragma unroll
    for (int k = 0; k < RPL; ++k)
        s_tg[t + 64 * k] = target[b * SEQ + t + 64 * k];
    __syncthreads();

    int myw[RPL];
    #pragma unroll
    for (int r = 0; r < RPL; ++r)
        myw[r] = words[b * SEQ + t * RPL + r];

    // column 0: colv[r] = D[t*8+1+r][0] = t*8+1+r ; prev_up = D[t*8][0]
    int colv[RPL];
    #pragma unroll
    for (int r = 0; r < RPL; ++r) colv[r] = t * RPL + 1 + r;
    int prev_up = t * RPL;

    const int NSTEP = SEQ + 63;     // 575
    for (int s = 1; s <= NSTEP; ++s) {
        int up_in = __shfl_up(colv[RPL - 1], 1, 64);   // D[t*8][j] from lane t-1
        const int j = s - t;
        if (t == 0) up_in = s;                          // D[0][j] = j
        if (j >= 1 && j <= SEQ) {
            const int tgj = s_tg[j - 1];
            // off-chain: mp[r] = min(left, diag - eq) + 1   (all prev-column regs)
            int mp[RPL];
            mp[0] = min(colv[0], prev_up - (myw[0] == tgj ? 1 : 0)) + 1;
            #pragma unroll
            for (int r = 1; r < RPL; ++r)
                mp[r] = min(colv[r], colv[r - 1] - (myw[r] == tgj ? 1 : 0)) + 1;
            // serial chain: 2 dependent ops per row
            int u = up_in;
            #pragma unroll
            for (int r = 0; r < RPL; ++r) {
                u = min(u + 1, mp[r]);
                colv[r] = u;
            }
            prev_up = up_in;
        }
    }

    if (t == 63)
        atomicAdd(out, (float)colv[RPL - 1] * (1.0f / ((float)BATCH * (float)SEQ)));
}

extern "C" void kernel_launch(void* const* d_in, const int* in_sizes, int n_in,
                              void* d_out, int out_size, void* d_ws, size_t ws_size,
                              hipStream_t stream) {
    const float* logits = (const float*)d_in[0];
    const int*   target = (const int*)d_in[1];

    int* words = (int*)d_ws;   // BATCH*SEQ ints
    float* out = (float*)d_out;

    argmax_kernel<<<BATCH * SEQ / 4, 256, 0, stream>>>(logits, words, out);
    editdist_kernel<<<BATCH, 64, 0, stream>>>(words, target, out);
}